// Round 1
// baseline (979.295 us; speedup 1.0000x reference)
//
#include <hip/hip_runtime.h>

#define B_ 2048
#define S_ 512
#define D_ 128
#define H_ 64
#define O_ 8
#define EPS 1e-5f

typedef __attribute__((ext_vector_type(8))) short bf16x8;
typedef __attribute__((ext_vector_type(4))) float f32x4;

// pack two f32 -> two bf16 (round-half-up; unbiased enough, 1 add + pack each)
__device__ __forceinline__ unsigned pk_bf16(float a, float b) {
  unsigned ua = __builtin_bit_cast(unsigned, a) + 0x8000u;
  unsigned ub = __builtin_bit_cast(unsigned, b) + 0x8000u;
  return (ua >> 16) | (ub & 0xffff0000u);
}

__device__ __forceinline__ bf16x8 pack8(f32x4 a, f32x4 b) {
  union { bf16x8 v; unsigned u[4]; } t;
  t.u[0] = pk_bf16(a[0], a[1]);
  t.u[1] = pk_bf16(a[2], a[3]);
  t.u[2] = pk_bf16(b[0], b[1]);
  t.u[3] = pk_bf16(b[2], b[3]);
  return t.v;
}

// One wave per block, 8 real batch rows per block (lanes c and c+8 duplicate).
// Transposed formulation: H[j][r], H_new = relu(W_ih * x_t^T + W_hh * H + bias)
//   A-frag (W tiles, registers, constant): A[m=lane&15][k=(lane>>4)*8+e]
//   B-frag (x / H):                        B[k=(lane>>4)*8+e][n=lane&15]
//   C/D:                                   D[m=(lane>>4)*4+e][n=lane&15]
// C->B relayout for the recurrence goes through a wave-private LDS buffer.
__global__ __launch_bounds__(64, 1) void rnn_fused(
    const float* __restrict__ x, const float* __restrict__ h0,
    const float* __restrict__ W_ih, const float* __restrict__ W_hh,
    const float* __restrict__ b_ih, const float* __restrict__ b_hh,
    float* __restrict__ hT) {
  const int lane = threadIdx.x;
  const int q = lane >> 4;          // quad 0..3
  const int c = lane & 15;          // column / batch-row slot
  const int row = blockIdx.x * 8 + (c & 7);

  __shared__ short Hlds[16][72];    // [r][j], stride 72 bf16 (pad vs 32-bank aliasing)

  // ---- x prefetch ring: 4 steps deep, B-frag addressing ----
  const float* xrow = x + (size_t)row * (S_ * D_) + q * 8;
  f32x4 ring[4][4][2];
#pragma unroll
  for (int s = 0; s < 4; ++s)
#pragma unroll
    for (int kt = 0; kt < 4; ++kt) {
      const float* p = xrow + s * D_ + kt * 32;
      ring[s][kt][0] = *(const f32x4*)p;
      ring[s][kt][1] = *(const f32x4*)(p + 4);
    }

  // ---- weights -> register A-fragments (constant across all 512 steps) ----
  bf16x8 Aih[4][4];                 // [jt][kt]  W_ih[16jt+c][32kt+8q+e]
#pragma unroll
  for (int jt = 0; jt < 4; ++jt)
#pragma unroll
    for (int kt = 0; kt < 4; ++kt) {
      const float* p = W_ih + (jt * 16 + c) * D_ + kt * 32 + q * 8;
      Aih[jt][kt] = pack8(*(const f32x4*)p, *(const f32x4*)(p + 4));
    }
  bf16x8 Ahh[4][2];                 // [jt][kt]  W_hh[16jt+c][32kt+8q+e]
#pragma unroll
  for (int jt = 0; jt < 4; ++jt)
#pragma unroll
    for (int kt = 0; kt < 2; ++kt) {
      const float* p = W_hh + (jt * 16 + c) * H_ + kt * 32 + q * 8;
      Ahh[jt][kt] = pack8(*(const f32x4*)p, *(const f32x4*)(p + 4));
    }

  f32x4 bias[4];                    // b_ih[j]+b_hh[j], j = 16jt+4q+e
#pragma unroll
  for (int jt = 0; jt < 4; ++jt) {
    f32x4 bi = *(const f32x4*)(b_ih + jt * 16 + q * 4);
    f32x4 bh = *(const f32x4*)(b_hh + jt * 16 + q * 4);
    bias[jt] = bi + bh;
  }

  // ---- initial hidden state as B-frags: H[k][r] = h0[r][k] ----
  bf16x8 Bh[2];
#pragma unroll
  for (int kt = 0; kt < 2; ++kt) {
    const float* p = h0 + row * H_ + kt * 32 + q * 8;
    Bh[kt] = pack8(*(const f32x4*)p, *(const f32x4*)(p + 4));
  }

  f32x4 acc[4];
  for (int tb = 0; tb < S_; tb += 4) {
#pragma unroll
    for (int u = 0; u < 4; ++u) {
      const int t = tb + u;
      // convert this step's x to bf16 B-frags
      bf16x8 Bx[4];
#pragma unroll
      for (int kt = 0; kt < 4; ++kt)
        Bx[kt] = pack8(ring[u][kt][0], ring[u][kt][1]);
      // refill ring slot for step t+4 (issued early, consumed 4 steps later)
      if (t + 4 < S_) {
        const float* p = xrow + (t + 4) * D_;
#pragma unroll
        for (int kt = 0; kt < 4; ++kt) {
          ring[u][kt][0] = *(const f32x4*)(p + kt * 32);
          ring[u][kt][1] = *(const f32x4*)(p + kt * 32 + 4);
        }
      }
#pragma unroll
      for (int jt = 0; jt < 4; ++jt) acc[jt] = bias[jt];
      // input projection: K=128 in 4 MFMA k-tiles
#pragma unroll
      for (int kt = 0; kt < 4; ++kt)
#pragma unroll
        for (int jt = 0; jt < 4; ++jt)
          acc[jt] = __builtin_amdgcn_mfma_f32_16x16x32_bf16(Aih[jt][kt], Bx[kt], acc[jt], 0, 0, 0);
      // recurrence: K=64 in 2 k-tiles
#pragma unroll
      for (int kt = 0; kt < 2; ++kt)
#pragma unroll
        for (int jt = 0; jt < 4; ++jt)
          acc[jt] = __builtin_amdgcn_mfma_f32_16x16x32_bf16(Ahh[jt][kt], Bh[kt], acc[jt], 0, 0, 0);
      // relu
#pragma unroll
      for (int jt = 0; jt < 4; ++jt)
#pragma unroll
        for (int e = 0; e < 4; ++e)
          acc[jt][e] = __builtin_fmaxf(acc[jt][e], 0.0f);
      // C-layout -> LDS [r][j] as packed bf16 pairs (wave-private; no barrier)
#pragma unroll
      for (int jt = 0; jt < 4; ++jt) {
        unsigned* wp = (unsigned*)&Hlds[c][jt * 16 + q * 4];
        wp[0] = pk_bf16(acc[jt][0], acc[jt][1]);
        wp[1] = pk_bf16(acc[jt][2], acc[jt][3]);
      }
      // read back as next step's B-frags: H[k=8q+e+32kt][r=c]
      Bh[0] = *(const bf16x8*)&Hlds[c][q * 8];
      Bh[1] = *(const bf16x8*)&Hlds[c][32 + q * 8];
    }
  }

  // final hidden state (post-relu fp32 still in acc) -> d_out hidden region
  if (c < 8) {
    float* op = hT + (size_t)row * H_;
#pragma unroll
    for (int jt = 0; jt < 4; ++jt)
      *(f32x4*)(op + jt * 16 + q * 4) = acc[jt];
  }
}

// ---- head: bn1 batch stats ----
__global__ void bn1_stats(const float* __restrict__ hT, float* __restrict__ ws) {
  __shared__ float ls[4][64], ls2[4][64];
  int tid = threadIdx.x;
  int j = tid & 63, rg = tid >> 6;
  int b0 = blockIdx.x * 128;
  float s = 0.f, s2 = 0.f;
  for (int i = 0; i < 32; ++i) {
    float v = hT[(size_t)(b0 + rg + i * 4) * H_ + j];
    s += v; s2 += v * v;
  }
  ls[rg][j] = s; ls2[rg][j] = s2;
  __syncthreads();
  if (tid < 64) {
    float a = ls[0][tid] + ls[1][tid] + ls[2][tid] + ls[3][tid];
    float a2 = ls2[0][tid] + ls2[1][tid] + ls2[2][tid] + ls2[3][tid];
    atomicAdd(&ws[tid], a);
    atomicAdd(&ws[64 + tid], a2);
  }
}

// ---- head: bn1 apply + fc1 + relu, z1 to ws, bn2 partial stats ----
__global__ void fc1_bn2(const float* __restrict__ hT, const float* __restrict__ bn1_g,
                        const float* __restrict__ bn1_b, const float* __restrict__ fc1_W,
                        const float* __restrict__ fc1_b, float* __restrict__ ws) {
  __shared__ float sh[1024], sw[1024], sc[64], sf[64], zz[256];
  int tid = threadIdx.x;
  int base = blockIdx.x * 1024;            // 16 rows * 64
  for (int i = tid; i < 1024; i += 256) { sh[i] = hT[base + i]; sw[i] = fc1_W[i]; }
  if (tid < 64) {
    float m = ws[tid] * (1.f / B_);
    float v = ws[64 + tid] * (1.f / B_) - m * m;
    float scl = bn1_g[tid] * rsqrtf(v + EPS);
    sc[tid] = scl;
    sf[tid] = bn1_b[tid] - m * scl;
  }
  __syncthreads();
  int r = tid >> 4, f = tid & 15;
  float a = fc1_b[f];
#pragma unroll 16
  for (int j = 0; j < 64; ++j)
    a += (sh[r * 64 + j] * sc[j] + sf[j]) * sw[f * 64 + j];
  a = fmaxf(a, 0.f);
  ws[160 + blockIdx.x * 256 + tid] = a;    // z1[(r0+r)*16+f]
  zz[tid] = a;
  __syncthreads();
  if (tid < 16) {
    float s = 0.f, s2 = 0.f;
    for (int rr = 0; rr < 16; ++rr) { float v = zz[rr * 16 + tid]; s += v; s2 += v * v; }
    atomicAdd(&ws[128 + tid], s);
    atomicAdd(&ws[144 + tid], s2);
  }
}

// ---- head: bn2 apply + fc2 -> out ----
__global__ void fc2_out(const float* __restrict__ ws, const float* __restrict__ bn2_g,
                        const float* __restrict__ bn2_b, const float* __restrict__ fc2_W,
                        const float* __restrict__ fc2_b, float* __restrict__ out) {
  __shared__ float sc2[16], sf2[16], w2[128], b2[8];
  int tid = threadIdx.x;
  if (tid < 16) {
    float m = ws[128 + tid] * (1.f / B_);
    float v = ws[144 + tid] * (1.f / B_) - m * m;
    float scl = bn2_g[tid] * rsqrtf(v + EPS);
    sc2[tid] = scl;
    sf2[tid] = bn2_b[tid] - m * scl;
  }
  if (tid < 128) w2[tid] = fc2_W[tid];
  if (tid < 8) b2[tid] = fc2_b[tid];
  __syncthreads();
  int gid = blockIdx.x * 256 + tid;
  int r = gid >> 3, o = gid & 7;
  const float* z = ws + 160 + r * 16;
  float a = b2[o];
#pragma unroll
  for (int f = 0; f < 16; ++f)
    a += (z[f] * sc2[f] + sf2[f]) * w2[o * 16 + f];
  out[gid] = a;
}

extern "C" void kernel_launch(void* const* d_in, const int* in_sizes, int n_in,
                              void* d_out, int out_size, void* d_ws, size_t ws_size,
                              hipStream_t stream) {
  (void)in_sizes; (void)n_in; (void)out_size; (void)ws_size;
  const float* x     = (const float*)d_in[0];
  const float* h0    = (const float*)d_in[1];
  const float* W_ih  = (const float*)d_in[2];
  const float* W_hh  = (const float*)d_in[3];
  const float* b_ih  = (const float*)d_in[4];
  const float* b_hh  = (const float*)d_in[5];
  const float* bn1_g = (const float*)d_in[6];
  const float* bn1_b = (const float*)d_in[7];
  const float* fc1_W = (const float*)d_in[8];
  const float* fc1_b = (const float*)d_in[9];
  const float* bn2_g = (const float*)d_in[10];
  const float* bn2_b = (const float*)d_in[11];
  const float* fc2_W = (const float*)d_in[12];
  const float* fc2_b = (const float*)d_in[13];

  float* out = (float*)d_out;
  float* hT  = out + B_ * O_;      // hidden-state output region, also head input
  float* ws  = (float*)d_ws;       // [0:64]sum1 [64:128]sq1 [128:144]sum2 [144:160]sq2 [160:+32768]z1

  hipMemsetAsync(d_ws, 0, 160 * sizeof(float), stream);
  rnn_fused<<<B_ / 8, 64, 0, stream>>>(x, h0, W_ih, W_hh, b_ih, b_hh, hT);
  bn1_stats<<<16, 256, 0, stream>>>(hT, ws);
  fc1_bn2<<<128, 256, 0, stream>>>(hT, bn1_g, bn1_b, fc1_W, fc1_b, ws);
  fc2_out<<<64, 256, 0, stream>>>(ws, bn2_g, bn2_b, fc2_W, fc2_b, out);
}

// Round 2
// 927.728 us; speedup vs baseline: 1.0556x; 1.0556x over previous
//
#include <hip/hip_runtime.h>

#define B_ 2048
#define S_ 512
#define D_ 128
#define H_ 64
#define O_ 8
#define EPS 1e-5f

typedef __attribute__((ext_vector_type(8))) short bf16x8;
typedef __attribute__((ext_vector_type(4))) float f32x4;

// pack two f32 -> two bf16 (round-half-up)
__device__ __forceinline__ unsigned pk_bf16(float a, float b) {
  unsigned ua = __builtin_bit_cast(unsigned, a) + 0x8000u;
  unsigned ub = __builtin_bit_cast(unsigned, b) + 0x8000u;
  return (ua >> 16) | (ub & 0xffff0000u);
}

__device__ __forceinline__ bf16x8 pack8(f32x4 a, f32x4 b) {
  union { bf16x8 v; unsigned u[4]; } t;
  t.u[0] = pk_bf16(a[0], a[1]);
  t.u[1] = pk_bf16(a[2], a[3]);
  t.u[2] = pk_bf16(b[0], b[1]);
  t.u[3] = pk_bf16(b[2], b[3]);
  return t.v;
}

// One wave per block, 16 DISTINCT batch rows per wave (128 blocks).
// Transposed formulation: H_new = relu(W_ih * x_t^T + W_hh * H + bias).
// KEY TRICK: relabel W_hh's k (column) order by
//   sigma(32kt + 8q + 4a + e) = 16*(2kt+a) + 4q + e
// at weight-pack time. Under sigma the MFMA C/D output registers ARE the
// next step's B-fragment: Bh0 = pack8(acc0,acc1), Bh1 = pack8(acc2,acc3).
// -> recurrent critical cycle = 2 MFMAs + relu + pack. No LDS, no shuffles.
// Input projection runs one step ahead into accP (x-only, off the cycle);
// the first recurrent MFMA consumes accP as its C operand.
__global__ __launch_bounds__(64) void rnn_fused(
    const float* __restrict__ x, const float* __restrict__ h0,
    const float* __restrict__ W_ih, const float* __restrict__ W_hh,
    const float* __restrict__ b_ih, const float* __restrict__ b_hh,
    float* __restrict__ hT) {
  const int lane = threadIdx.x;
  const int q = lane >> 4;          // quad 0..3
  const int c = lane & 15;          // column = batch-row slot (all distinct)
  const int row = blockIdx.x * 16 + c;

  // ---- x prefetch ring: 4 steps deep, standard B-frag addressing ----
  const float* xrow = x + (size_t)row * (S_ * D_) + q * 8;
  f32x4 ring[4][4][2];
#pragma unroll
  for (int s = 0; s < 4; ++s)
#pragma unroll
    for (int kt = 0; kt < 4; ++kt) {
      const float* p = xrow + s * D_ + kt * 32;
      ring[s][kt][0] = *(const f32x4*)p;
      ring[s][kt][1] = *(const f32x4*)(p + 4);
    }

  // ---- W_ih -> A-frags, standard k-order: A[m=16jt+c][k=32kt+8q+e] ----
  bf16x8 Aih[4][4];
#pragma unroll
  for (int jt = 0; jt < 4; ++jt)
#pragma unroll
    for (int kt = 0; kt < 4; ++kt) {
      const float* p = W_ih + (jt * 16 + c) * D_ + kt * 32 + q * 8;
      Aih[jt][kt] = pack8(*(const f32x4*)p, *(const f32x4*)(p + 4));
    }
  // ---- W_hh -> A-frags in SIGMA k-order:
  //   elem (kt, 4a+e) = W_hh[16jt+c][16*(2kt+a) + 4q + e] ----
  bf16x8 Ahh[4][2];
#pragma unroll
  for (int jt = 0; jt < 4; ++jt)
#pragma unroll
    for (int kt = 0; kt < 2; ++kt) {
      const float* p = W_hh + (jt * 16 + c) * H_ + kt * 32 + q * 4;
      Ahh[jt][kt] = pack8(*(const f32x4*)p, *(const f32x4*)(p + 16));
    }

  f32x4 bias[4];                    // (b_ih+b_hh)[16jt + 4q + e]
#pragma unroll
  for (int jt = 0; jt < 4; ++jt) {
    f32x4 bi = *(const f32x4*)(b_ih + jt * 16 + q * 4);
    f32x4 bh = *(const f32x4*)(b_hh + jt * 16 + q * 4);
    bias[jt] = bi + bh;
  }

  // ---- initial hidden state as sigma-order B-frags: elem(kt,4a+e)=h0[row][16(2kt+a)+4q+e]
  const float* h0r = h0 + (size_t)row * H_;
  bf16x8 Bh[2];
#pragma unroll
  for (int kt = 0; kt < 2; ++kt)
    Bh[kt] = pack8(*(const f32x4*)(h0r + kt * 32 + q * 4),
                   *(const f32x4*)(h0r + kt * 32 + 16 + q * 4));

  // ---- prologue: accP for step 0 = bias + W_ih * x_0^T ----
  f32x4 accP[4];
#pragma unroll
  for (int jt = 0; jt < 4; ++jt) accP[jt] = bias[jt];
  {
    bf16x8 Bx[4];
#pragma unroll
    for (int kt = 0; kt < 4; ++kt) Bx[kt] = pack8(ring[0][kt][0], ring[0][kt][1]);
#pragma unroll
    for (int kt = 0; kt < 4; ++kt)
#pragma unroll
      for (int jt = 0; jt < 4; ++jt)
        accP[jt] = __builtin_amdgcn_mfma_f32_16x16x32_bf16(Aih[jt][kt], Bx[kt], accP[jt], 0, 0, 0);
  }

  f32x4 acc[4];
  for (int tb = 0; tb < S_; tb += 4) {
#pragma unroll
    for (int u = 0; u < 4; ++u) {
      const int t = tb + u;
      const int slot = (u + 1) & 3;
      // recurrent chain for step t (C operand = accP, the precomputed proj)
#pragma unroll
      for (int jt = 0; jt < 4; ++jt)
        acc[jt] = __builtin_amdgcn_mfma_f32_16x16x32_bf16(Ahh[jt][0], Bh[0], accP[jt], 0, 0, 0);
#pragma unroll
      for (int jt = 0; jt < 4; ++jt)
        acc[jt] = __builtin_amdgcn_mfma_f32_16x16x32_bf16(Ahh[jt][1], Bh[1], acc[jt], 0, 0, 0);
      // pack next step's x B-frags from the ring (independent of the chain)
      bf16x8 Bx[4];
#pragma unroll
      for (int kt = 0; kt < 4; ++kt)
        Bx[kt] = pack8(ring[slot][kt][0], ring[slot][kt][1]);
      // refill the consumed slot with x_{t+5}
      if (t + 5 < S_) {
        const float* p = xrow + (t + 5) * D_;
#pragma unroll
        for (int kt = 0; kt < 4; ++kt) {
          ring[slot][kt][0] = *(const f32x4*)(p + kt * 32);
          ring[slot][kt][1] = *(const f32x4*)(p + kt * 32 + 4);
        }
      }
      // relu; then C/D registers ARE the next B-frags under sigma
#pragma unroll
      for (int jt = 0; jt < 4; ++jt)
#pragma unroll
        for (int e = 0; e < 4; ++e)
          acc[jt][e] = __builtin_fmaxf(acc[jt][e], 0.0f);
      Bh[0] = pack8(acc[0], acc[1]);
      Bh[1] = pack8(acc[2], acc[3]);
      // projection for step t+1 (off the critical cycle; interleaves with above)
#pragma unroll
      for (int jt = 0; jt < 4; ++jt) accP[jt] = bias[jt];
#pragma unroll
      for (int kt = 0; kt < 4; ++kt)
#pragma unroll
        for (int jt = 0; jt < 4; ++jt)
          accP[jt] = __builtin_amdgcn_mfma_f32_16x16x32_bf16(Aih[jt][kt], Bx[kt], accP[jt], 0, 0, 0);
    }
  }

  // final hidden state (post-relu fp32 still in acc) -> hT
  float* op = hT + (size_t)row * H_;
#pragma unroll
  for (int jt = 0; jt < 4; ++jt)
    *(f32x4*)(op + jt * 16 + q * 4) = acc[jt];
}

// ---- head: bn1 batch stats ----
__global__ void bn1_stats(const float* __restrict__ hT, float* __restrict__ ws) {
  __shared__ float ls[4][64], ls2[4][64];
  int tid = threadIdx.x;
  int j = tid & 63, rg = tid >> 6;
  int b0 = blockIdx.x * 128;
  float s = 0.f, s2 = 0.f;
  for (int i = 0; i < 32; ++i) {
    float v = hT[(size_t)(b0 + rg + i * 4) * H_ + j];
    s += v; s2 += v * v;
  }
  ls[rg][j] = s; ls2[rg][j] = s2;
  __syncthreads();
  if (tid < 64) {
    float a = ls[0][tid] + ls[1][tid] + ls[2][tid] + ls[3][tid];
    float a2 = ls2[0][tid] + ls2[1][tid] + ls2[2][tid] + ls2[3][tid];
    atomicAdd(&ws[tid], a);
    atomicAdd(&ws[64 + tid], a2);
  }
}

// ---- head: bn1 apply + fc1 + relu, z1 to ws, bn2 partial stats ----
__global__ void fc1_bn2(const float* __restrict__ hT, const float* __restrict__ bn1_g,
                        const float* __restrict__ bn1_b, const float* __restrict__ fc1_W,
                        const float* __restrict__ fc1_b, float* __restrict__ ws) {
  __shared__ float sh[1024], sw[1024], sc[64], sf[64], zz[256];
  int tid = threadIdx.x;
  int base = blockIdx.x * 1024;            // 16 rows * 64
  for (int i = tid; i < 1024; i += 256) { sh[i] = hT[base + i]; sw[i] = fc1_W[i]; }
  if (tid < 64) {
    float m = ws[tid] * (1.f / B_);
    float v = ws[64 + tid] * (1.f / B_) - m * m;
    float scl = bn1_g[tid] * rsqrtf(v + EPS);
    sc[tid] = scl;
    sf[tid] = bn1_b[tid] - m * scl;
  }
  __syncthreads();
  int r = tid >> 4, f = tid & 15;
  float a = fc1_b[f];
#pragma unroll 16
  for (int j = 0; j < 64; ++j)
    a += (sh[r * 64 + j] * sc[j] + sf[j]) * sw[f * 64 + j];
  a = fmaxf(a, 0.f);
  ws[160 + blockIdx.x * 256 + tid] = a;    // z1[(r0+r)*16+f]
  zz[tid] = a;
  __syncthreads();
  if (tid < 16) {
    float s = 0.f, s2 = 0.f;
    for (int rr = 0; rr < 16; ++rr) { float v = zz[rr * 16 + tid]; s += v; s2 += v * v; }
    atomicAdd(&ws[128 + tid], s);
    atomicAdd(&ws[144 + tid], s2);
  }
}

// ---- head: bn2 apply + fc2 -> out ----
__global__ void fc2_out(const float* __restrict__ ws, const float* __restrict__ bn2_g,
                        const float* __restrict__ bn2_b, const float* __restrict__ fc2_W,
                        const float* __restrict__ fc2_b, float* __restrict__ out) {
  __shared__ float sc2[16], sf2[16], w2[128], b2[8];
  int tid = threadIdx.x;
  if (tid < 16) {
    float m = ws[128 + tid] * (1.f / B_);
    float v = ws[144 + tid] * (1.f / B_) - m * m;
    float scl = bn2_g[tid] * rsqrtf(v + EPS);
    sc2[tid] = scl;
    sf2[tid] = bn2_b[tid] - m * scl;
  }
  if (tid < 128) w2[tid] = fc2_W[tid];
  if (tid < 8) b2[tid] = fc2_b[tid];
  __syncthreads();
  int gid = blockIdx.x * 256 + tid;
  int r = gid >> 3, o = gid & 7;
  const float* z = ws + 160 + r * 16;
  float a = b2[o];
#pragma unroll
  for (int f = 0; f < 16; ++f)
    a += (z[f] * sc2[f] + sf2[f]) * w2[o * 16 + f];
  out[gid] = a;
}

extern "C" void kernel_launch(void* const* d_in, const int* in_sizes, int n_in,
                              void* d_out, int out_size, void* d_ws, size_t ws_size,
                              hipStream_t stream) {
  (void)in_sizes; (void)n_in; (void)out_size; (void)ws_size;
  const float* x     = (const float*)d_in[0];
  const float* h0    = (const float*)d_in[1];
  const float* W_ih  = (const float*)d_in[2];
  const float* W_hh  = (const float*)d_in[3];
  const float* b_ih  = (const float*)d_in[4];
  const float* b_hh  = (const float*)d_in[5];
  const float* bn1_g = (const float*)d_in[6];
  const float* bn1_b = (const float*)d_in[7];
  const float* fc1_W = (const float*)d_in[8];
  const float* fc1_b = (const float*)d_in[9];
  const float* bn2_g = (const float*)d_in[10];
  const float* bn2_b = (const float*)d_in[11];
  const float* fc2_W = (const float*)d_in[12];
  const float* fc2_b = (const float*)d_in[13];

  float* out = (float*)d_out;
  float* hT  = out + B_ * O_;      // hidden-state output region, also head input
  float* ws  = (float*)d_ws;       // [0:64]sum1 [64:128]sq1 [128:144]sum2 [144:160]sq2 [160:+32768]z1

  hipMemsetAsync(d_ws, 0, 160 * sizeof(float), stream);
  rnn_fused<<<B_ / 16, 64, 0, stream>>>(x, h0, W_ih, W_hh, b_ih, b_hh, hT);
  bn1_stats<<<16, 256, 0, stream>>>(hT, ws);
  fc1_bn2<<<128, 256, 0, stream>>>(hT, bn1_g, bn1_b, fc1_W, fc1_b, ws);
  fc2_out<<<64, 256, 0, stream>>>(ws, bn2_g, bn2_b, fc2_W, fc2_b, out);
}

// Round 3
// 747.908 us; speedup vs baseline: 1.3094x; 1.2404x over previous
//
#include <hip/hip_runtime.h>

#define B_ 2048
#define S_ 512
#define D_ 128
#define H_ 64
#define O_ 8
#define EPS 1e-5f

#define CHUNK 16
#define NCHUNK (S_ / CHUNK)   // 32
#define PSTRIDE 68            // floats per row-slot: 16B-aligned, 2-way banks (free)

typedef __attribute__((ext_vector_type(8))) short bf16x8;
typedef __attribute__((ext_vector_type(4))) float f32x4;

// pack two f32 -> two bf16 (round-half-up)
__device__ __forceinline__ unsigned pk_bf16(float a, float b) {
  unsigned ua = __builtin_bit_cast(unsigned, a) + 0x8000u;
  unsigned ub = __builtin_bit_cast(unsigned, b) + 0x8000u;
  return (ua >> 16) | (ub & 0xffff0000u);
}

__device__ __forceinline__ bf16x8 pack8(f32x4 a, f32x4 b) {
  union { bf16x8 v; unsigned u[4]; } t;
  t.u[0] = pk_bf16(a[0], a[1]);
  t.u[1] = pk_bf16(a[2], a[3]);
  t.u[2] = pk_bf16(b[0], b[1]);
  t.u[3] = pk_bf16(b[2], b[3]);
  return t.v;
}

// Producer/consumer block: 16 batch rows, 8 waves.
//   waves 0..6: projection P_t = bias + W_ih * x_t^T for a 16-step chunk,
//               written to double-buffered LDS in MFMA C-layout (f32).
//   wave 7:     serial recurrence h = relu(W_hh*h + P_t), LDS-only reads.
// Sigma trick (verified R2): W_hh packed with k-order
// sigma(32kt+8q+4a+e)=16(2kt+a)+4q+e so the MFMA C/D regs ARE the next
// step's B-fragment (Bh0=pack8(acc0,acc1), Bh1=pack8(acc2,acc3)).
__global__ __launch_bounds__(512, 2) void rnn_fused(
    const float* __restrict__ x, const float* __restrict__ h0,
    const float* __restrict__ W_ih, const float* __restrict__ W_hh,
    const float* __restrict__ b_ih, const float* __restrict__ b_hh,
    float* __restrict__ hT) {
  extern __shared__ float Plds[];   // [2][CHUNK][16][PSTRIDE]
  const int tid = threadIdx.x;
  const int w = tid >> 6;           // wave id 0..7
  const int lane = tid & 63;
  const int q = lane >> 4;          // quad 0..3
  const int c = lane & 15;          // column = batch-row slot
  const int row = blockIdx.x * 16 + c;

  // ---------------- producer state (waves 0..6) ----------------
  const float* xrow = x + (size_t)row * (S_ * D_) + q * 8;
  bf16x8 Aih[4][4];
  f32x4 bias[4];
  // ---------------- consumer state (wave 7) ----------------
  bf16x8 Ahh[4][2];
  bf16x8 Bh[2];
  f32x4 acc[4];

  if (w < 7) {
    // W_ih -> A-frags, standard k-order: A[m=16jt+c][k=32kt+8q+e]
#pragma unroll
    for (int jt = 0; jt < 4; ++jt)
#pragma unroll
      for (int kt = 0; kt < 4; ++kt) {
        const float* p = W_ih + (jt * 16 + c) * D_ + kt * 32 + q * 8;
        Aih[jt][kt] = pack8(*(const f32x4*)p, *(const f32x4*)(p + 4));
      }
#pragma unroll
    for (int jt = 0; jt < 4; ++jt) {
      f32x4 bi = *(const f32x4*)(b_ih + jt * 16 + q * 4);
      f32x4 bh = *(const f32x4*)(b_hh + jt * 16 + q * 4);
      bias[jt] = bi + bh;
    }
  } else {
    // W_hh -> A-frags in SIGMA k-order (verified R2)
#pragma unroll
    for (int jt = 0; jt < 4; ++jt)
#pragma unroll
      for (int kt = 0; kt < 2; ++kt) {
        const float* p = W_hh + (jt * 16 + c) * H_ + kt * 32 + q * 4;
        Ahh[jt][kt] = pack8(*(const f32x4*)p, *(const f32x4*)(p + 16));
      }
    // h0 as sigma-order B-frags
    const float* h0r = h0 + (size_t)row * H_;
#pragma unroll
    for (int kt = 0; kt < 2; ++kt)
      Bh[kt] = pack8(*(const f32x4*)(h0r + kt * 32 + q * 4),
                     *(const f32x4*)(h0r + kt * 32 + 16 + q * 4));
  }

  f32x4 xb[2][8];
  auto loadx = [&](f32x4* d, int t) {
    const float* p = xrow + (size_t)t * D_;
#pragma unroll
    for (int kt = 0; kt < 4; ++kt) {
      d[2 * kt]     = *(const f32x4*)(p + kt * 32);
      d[2 * kt + 1] = *(const f32x4*)(p + kt * 32 + 4);
    }
  };

  // producer: compute+store step s of chunk (from staged regs) into buf
  auto pstep = [&](const f32x4* xd, int s, int buf) {
    bf16x8 Bx[4];
#pragma unroll
    for (int kt = 0; kt < 4; ++kt) Bx[kt] = pack8(xd[2 * kt], xd[2 * kt + 1]);
    f32x4 a[4];
#pragma unroll
    for (int jt = 0; jt < 4; ++jt) a[jt] = bias[jt];
#pragma unroll
    for (int kt = 0; kt < 4; ++kt)
#pragma unroll
      for (int jt = 0; jt < 4; ++jt)
        a[jt] = __builtin_amdgcn_mfma_f32_16x16x32_bf16(Aih[jt][kt], Bx[kt], a[jt], 0, 0, 0);
    float* dst = Plds + ((size_t)(buf * CHUNK + s) * 16 + c) * PSTRIDE + q * 4;
#pragma unroll
    for (int jt = 0; jt < 4; ++jt)
      *(f32x4*)(dst + jt * 16) = a[jt];
  };

  // producer: whole chunk ck into buffer buf (steps w, w+7, w+14)
  const int ns = (CHUNK - 1 - w) / 7 + 1;   // 3 for w<2 else 2
  auto produce = [&](int ck, int buf) {
    const int t0 = ck * CHUNK;
    loadx(xb[0], t0 + w);
#pragma unroll
    for (int i = 0; i < 3; ++i) {
      if (i < ns) {
        if (i + 1 < ns) loadx(xb[(i + 1) & 1], t0 + w + 7 * (i + 1));
        pstep(xb[i & 1], w + 7 * i, buf);
      }
    }
  };

  // consumer: run CHUNK recurrence steps from buffer buf
  auto consume = [&](int buf) {
    const float* Pb = Plds + (size_t)buf * CHUNK * 16 * PSTRIDE + c * PSTRIDE + q * 4;
    f32x4 accP[4];
#pragma unroll
    for (int jt = 0; jt < 4; ++jt) accP[jt] = *(const f32x4*)(Pb + jt * 16);
#pragma unroll 1
    for (int s = 0; s < CHUNK; ++s) {
      f32x4 accN[4];
#pragma unroll
      for (int jt = 0; jt < 4; ++jt) accN[jt] = accP[jt];
      if (s + 1 < CHUNK) {
        const float* Pn = Pb + (size_t)(s + 1) * 16 * PSTRIDE;
#pragma unroll
        for (int jt = 0; jt < 4; ++jt) accN[jt] = *(const f32x4*)(Pn + jt * 16);
      }
#pragma unroll
      for (int jt = 0; jt < 4; ++jt)
        acc[jt] = __builtin_amdgcn_mfma_f32_16x16x32_bf16(Ahh[jt][0], Bh[0], accP[jt], 0, 0, 0);
#pragma unroll
      for (int jt = 0; jt < 4; ++jt)
        acc[jt] = __builtin_amdgcn_mfma_f32_16x16x32_bf16(Ahh[jt][1], Bh[1], acc[jt], 0, 0, 0);
#pragma unroll
      for (int jt = 0; jt < 4; ++jt)
#pragma unroll
        for (int e = 0; e < 4; ++e)
          acc[jt][e] = __builtin_fmaxf(acc[jt][e], 0.0f);
      Bh[0] = pack8(acc[0], acc[1]);
      Bh[1] = pack8(acc[2], acc[3]);
#pragma unroll
      for (int jt = 0; jt < 4; ++jt) accP[jt] = accN[jt];
    }
  };

  // ---- pipeline: producers stay one chunk ahead ----
  if (w < 7) produce(0, 0);
  __syncthreads();
  for (int ck = 0; ck < NCHUNK; ++ck) {
    if (w < 7) {
      if (ck + 1 < NCHUNK) produce(ck + 1, (ck + 1) & 1);
    } else {
      consume(ck & 1);
    }
    __syncthreads();
  }

  if (w == 7) {
    float* op = hT + (size_t)row * H_;
#pragma unroll
    for (int jt = 0; jt < 4; ++jt)
      *(f32x4*)(op + jt * 16 + q * 4) = acc[jt];
  }
}

// ---- head: bn1 batch stats ----
__global__ void bn1_stats(const float* __restrict__ hT, float* __restrict__ ws) {
  __shared__ float ls[4][64], ls2[4][64];
  int tid = threadIdx.x;
  int j = tid & 63, rg = tid >> 6;
  int b0 = blockIdx.x * 128;
  float s = 0.f, s2 = 0.f;
  for (int i = 0; i < 32; ++i) {
    float v = hT[(size_t)(b0 + rg + i * 4) * H_ + j];
    s += v; s2 += v * v;
  }
  ls[rg][j] = s; ls2[rg][j] = s2;
  __syncthreads();
  if (tid < 64) {
    float a = ls[0][tid] + ls[1][tid] + ls[2][tid] + ls[3][tid];
    float a2 = ls2[0][tid] + ls2[1][tid] + ls2[2][tid] + ls2[3][tid];
    atomicAdd(&ws[tid], a);
    atomicAdd(&ws[64 + tid], a2);
  }
}

// ---- head: bn1 apply + fc1 + relu, z1 to ws, bn2 partial stats ----
__global__ void fc1_bn2(const float* __restrict__ hT, const float* __restrict__ bn1_g,
                        const float* __restrict__ bn1_b, const float* __restrict__ fc1_W,
                        const float* __restrict__ fc1_b, float* __restrict__ ws) {
  __shared__ float sh[1024], sw[1024], sc[64], sf[64], zz[256];
  int tid = threadIdx.x;
  int base = blockIdx.x * 1024;            // 16 rows * 64
  for (int i = tid; i < 1024; i += 256) { sh[i] = hT[base + i]; sw[i] = fc1_W[i]; }
  if (tid < 64) {
    float m = ws[tid] * (1.f / B_);
    float v = ws[64 + tid] * (1.f / B_) - m * m;
    float scl = bn1_g[tid] * rsqrtf(v + EPS);
    sc[tid] = scl;
    sf[tid] = bn1_b[tid] - m * scl;
  }
  __syncthreads();
  int r = tid >> 4, f = tid & 15;
  float a = fc1_b[f];
#pragma unroll 16
  for (int j = 0; j < 64; ++j)
    a += (sh[r * 64 + j] * sc[j] + sf[j]) * sw[f * 64 + j];
  a = fmaxf(a, 0.f);
  ws[160 + blockIdx.x * 256 + tid] = a;    // z1[(r0+r)*16+f]
  zz[tid] = a;
  __syncthreads();
  if (tid < 16) {
    float s = 0.f, s2 = 0.f;
    for (int rr = 0; rr < 16; ++rr) { float v = zz[rr * 16 + tid]; s += v; s2 += v * v; }
    atomicAdd(&ws[128 + tid], s);
    atomicAdd(&ws[144 + tid], s2);
  }
}

// ---- head: bn2 apply + fc2 -> out ----
__global__ void fc2_out(const float* __restrict__ ws, const float* __restrict__ bn2_g,
                        const float* __restrict__ bn2_b, const float* __restrict__ fc2_W,
                        const float* __restrict__ fc2_b, float* __restrict__ out) {
  __shared__ float sc2[16], sf2[16], w2[128], b2[8];
  int tid = threadIdx.x;
  if (tid < 16) {
    float m = ws[128 + tid] * (1.f / B_);
    float v = ws[144 + tid] * (1.f / B_) - m * m;
    float scl = bn2_g[tid] * rsqrtf(v + EPS);
    sc2[tid] = scl;
    sf2[tid] = bn2_b[tid] - m * scl;
  }
  if (tid < 128) w2[tid] = fc2_W[tid];
  if (tid < 8) b2[tid] = fc2_b[tid];
  __syncthreads();
  int gid = blockIdx.x * 256 + tid;
  int r = gid >> 3, o = gid & 7;
  const float* z = ws + 160 + r * 16;
  float a = b2[o];
#pragma unroll
  for (int f = 0; f < 16; ++f)
    a += (z[f] * sc2[f] + sf2[f]) * w2[o * 16 + f];
  out[gid] = a;
}

extern "C" void kernel_launch(void* const* d_in, const int* in_sizes, int n_in,
                              void* d_out, int out_size, void* d_ws, size_t ws_size,
                              hipStream_t stream) {
  (void)in_sizes; (void)n_in; (void)out_size; (void)ws_size;
  const float* x     = (const float*)d_in[0];
  const float* h0    = (const float*)d_in[1];
  const float* W_ih  = (const float*)d_in[2];
  const float* W_hh  = (const float*)d_in[3];
  const float* b_ih  = (const float*)d_in[4];
  const float* b_hh  = (const float*)d_in[5];
  const float* bn1_g = (const float*)d_in[6];
  const float* bn1_b = (const float*)d_in[7];
  const float* fc1_W = (const float*)d_in[8];
  const float* fc1_b = (const float*)d_in[9];
  const float* bn2_g = (const float*)d_in[10];
  const float* bn2_b = (const float*)d_in[11];
  const float* fc2_W = (const float*)d_in[12];
  const float* fc2_b = (const float*)d_in[13];

  float* out = (float*)d_out;
  float* hT  = out + B_ * O_;      // hidden-state output region, also head input
  float* ws  = (float*)d_ws;       // [0:64]sum1 [64:128]sq1 [128:144]sum2 [144:160]sq2 [160:+32768]z1

  const int pbytes = 2 * CHUNK * 16 * PSTRIDE * 4;   // 139264 B dynamic LDS
  static bool attr_done = false;
  hipFuncSetAttribute((const void*)rnn_fused,
                      hipFuncAttributeMaxDynamicSharedMemorySize, pbytes);
  (void)attr_done;

  hipMemsetAsync(d_ws, 0, 160 * sizeof(float), stream);
  rnn_fused<<<B_ / 16, 512, pbytes, stream>>>(x, h0, W_ih, W_hh, b_ih, b_hh, hT);
  bn1_stats<<<16, 256, 0, stream>>>(hT, ws);
  fc1_bn2<<<128, 256, 0, stream>>>(hT, bn1_g, bn1_b, fc1_W, fc1_b, ws);
  fc2_out<<<64, 256, 0, stream>>>(ws, bn2_g, bn2_b, fc2_W, fc2_b, out);
}